// Round 24
// baseline (119.446 us; speedup 1.0000x reference)
//
#include <hip/hip_runtime.h>

typedef short short8 __attribute__((ext_vector_type(8)));
typedef float f32x4 __attribute__((ext_vector_type(4)));
typedef unsigned long long u64;

#define NE 1024
#define D 64
#define HW 4096
#define MARGIN 3.0e-3f     // t-space margin (proven R3/R5/R12-R22); acc-space = M/2
#define FLT_MAX_F 3.402823466e+38f
#define MST 33             // mask32 row stride in u32 (pad)

// ws: bn f32[1024]@0 ; ebf u16[65536]@4096
#define WS_BN  0
#define WS_EBF 4096

__device__ __forceinline__ unsigned short f2bf(float f) {   // RNE f32->bf16
    unsigned u = __float_as_uint(f);
    return (unsigned short)((u + 0x7fffu + ((u >> 16) & 1u)) >> 16);
}

// numpy pairwise sum of squares, n=64 (frozen — exact since R2)
__device__ __forceinline__ float np_sum64_sq(const float* v) {
    float s[8];
#pragma unroll
    for (int j = 0; j < 8; ++j) s[j] = __fmul_rn(v[j], v[j]);
#pragma unroll
    for (int i = 8; i < 64; i += 8) {
#pragma unroll
        for (int j = 0; j < 8; ++j)
            s[j] = __fadd_rn(s[j], __fmul_rn(v[i + j], v[i + j]));
    }
    return __fadd_rn(__fadd_rn(__fadd_rn(s[0], s[1]), __fadd_rn(s[2], s[3])),
                     __fadd_rn(__fadd_rn(s[4], s[5]), __fadd_rn(s[6], s[7])));
}

__global__ __launch_bounds__(256) void kP_prep(
        const float* __restrict__ cb, float* __restrict__ bn,
        unsigned short* __restrict__ ebf) {
    const int gid = blockIdx.x * 256 + threadIdx.x;   // 65536 threads
    ebf[gid] = f2bf(cb[gid]);
    if (gid < NE) {
        float row[D];
        const float4* r4 = reinterpret_cast<const float4*>(cb + (size_t)gid * D);
#pragma unroll
        for (int i = 0; i < 16; ++i) {
            float4 v = r4[i];
            row[4*i+0] = v.x; row[4*i+1] = v.y; row[4*i+2] = v.z; row[4*i+3] = v.w;
        }
        bn[gid] = np_sum64_sq(row);
    }
}

// BARRIER-FREE main loop: 256 thr / 4 waves, 32 tokens/wave (128/block).
// A-fragments read per-iteration from L2-resident ebf directly into registers
// (no LDS staging, no per-phase __syncthreads -> no vmcnt(0) drains; the
// compiler software-pipelines the loads). Two passes (R20-proven semantics):
// A = per-token max fold, B = bit-identical recompute + u32 lane-local marks.
__global__ __launch_bounds__(256, 2) void k_mega(
        const float* __restrict__ in, const unsigned short* __restrict__ ebf,
        const float* __restrict__ bn_g, const float* __restrict__ cb,
        float* __restrict__ out) {
    __shared__ float sbn[NE];                     // 4 KB (-0.5*bn)
    __shared__ unsigned mask32[128 * MST];        // 16.9 KB
    __shared__ unsigned short win_s[128];

    const int tid  = threadIdx.x;
    const int lane = tid & 63, w = tid >> 6;      // w in 0..3
    const int lcol = lane & 15, lhi = lane >> 4, lrow = lhi * 4;
    const int tokw = blockIdx.x * 128 + w * 32;   // wave's 32 tokens
    const int b = tokw >> 12, hwb = tokw & 4095;

#pragma unroll
    for (int i = 0; i < 4; ++i)
        sbn[tid + i * 256] = __fmul_rn(-0.5f, bn_g[tid + i * 256]);  // exact *0.5

    // B fragments (frozen build, proven R4-R22): 32 tokens -> 4 frags
    const float* xbase = in + (size_t)b * (D * HW);
    const int hw0 = hwb + lcol, hw1 = hw0 + 16;
    const int kb = lhi * 8;
    short8 B00, B01, B10, B11;
    {
        const float* p;
        p = xbase + (size_t)kb * HW + hw0;
#pragma unroll
        for (int j = 0; j < 8; ++j) B00[j] = (short)f2bf(p[(size_t)j * HW]);
        p = xbase + (size_t)(kb + 32) * HW + hw0;
#pragma unroll
        for (int j = 0; j < 8; ++j) B01[j] = (short)f2bf(p[(size_t)j * HW]);
        p = xbase + (size_t)kb * HW + hw1;
#pragma unroll
        for (int j = 0; j < 8; ++j) B10[j] = (short)f2bf(p[(size_t)j * HW]);
        p = xbase + (size_t)(kb + 32) * HW + hw1;
#pragma unroll
        for (int j = 0; j < 8; ++j) B11[j] = (short)f2bf(p[(size_t)j * HW]);
    }
    __syncthreads();                              // sbn visible (barrier #1)

    // per-lane A-frag base: code group g covers codes [16g,16g+16)
    const unsigned short* abase = ebf + (size_t)lcol * 64 + lhi * 8;

    // ---- pass A: per-token MAX of acc over all 64 code groups ----
    f32x4 vA = {-FLT_MAX_F, -FLT_MAX_F, -FLT_MAX_F, -FLT_MAX_F};  // token grp 0
    f32x4 vB = vA;                                                 // token grp 1
#pragma unroll 4
    for (int g = 0; g < 64; ++g) {
        const unsigned short* ap = abase + (size_t)g * 1024;   // g*16*64
        short8 a0 = *(const short8*)(ap);
        short8 a1 = *(const short8*)(ap + 32);
        f32x4 cin = *(const f32x4*)(sbn + g * 16 + lrow);      // C-init (-bn/2)
        f32x4 acc = cin;
        acc = __builtin_amdgcn_mfma_f32_16x16x32_bf16(a0, B00, acc, 0, 0, 0);
        acc = __builtin_amdgcn_mfma_f32_16x16x32_bf16(a1, B01, acc, 0, 0, 0);
        f32x4 ac2 = cin;
        ac2 = __builtin_amdgcn_mfma_f32_16x16x32_bf16(a0, B10, ac2, 0, 0, 0);
        ac2 = __builtin_amdgcn_mfma_f32_16x16x32_bf16(a1, B11, ac2, 0, 0, 0);
#pragma unroll
        for (int r = 0; r < 4; ++r) {
            vA[r] = fmaxf(vA[r], acc[r]);
            vB[r] = fmaxf(vB[r], ac2[r]);
        }
    }
    float v0 = fmaxf(fmaxf(vA[0], vA[1]), fmaxf(vA[2], vA[3]));
    float v1 = fmaxf(fmaxf(vB[0], vB[1]), fmaxf(vB[2], vB[3]));
    v0 = fmaxf(v0, __shfl_xor(v0, 16)); v0 = fmaxf(v0, __shfl_xor(v0, 32));
    v1 = fmaxf(v1, __shfl_xor(v1, 16)); v1 = fmaxf(v1, __shfl_xor(v1, 32));
    const float athr0 = v0 - 0.5f * MARGIN;       // acc-space threshold (R18)
    const float athr1 = v1 - 0.5f * MARGIN;
    const int tA = w * 32 + lcol, tB = tA + 16;   // token-local indices

    // ---- pass B: bit-identical recompute; u32 lane-local marks (R20) ----
    for (int c = 0; c < 8; ++c) {
        unsigned m0 = 0, m1 = 0;
#pragma unroll
        for (int cg = 0; cg < 8; ++cg) {
            const int g = c * 8 + cg;
            const unsigned short* ap = abase + (size_t)g * 1024;
            short8 a0 = *(const short8*)(ap);
            short8 a1 = *(const short8*)(ap + 32);
            f32x4 cin = *(const f32x4*)(sbn + g * 16 + lrow);
            f32x4 acc = cin;
            acc = __builtin_amdgcn_mfma_f32_16x16x32_bf16(a0, B00, acc, 0, 0, 0);
            acc = __builtin_amdgcn_mfma_f32_16x16x32_bf16(a1, B01, acc, 0, 0, 0);
            f32x4 ac2 = cin;
            ac2 = __builtin_amdgcn_mfma_f32_16x16x32_bf16(a0, B10, ac2, 0, 0, 0);
            ac2 = __builtin_amdgcn_mfma_f32_16x16x32_bf16(a1, B11, ac2, 0, 0, 0);
#pragma unroll
            for (int r = 0; r < 4; ++r) {
                if (acc[r] >= athr0) m0 |= (1u << (cg * 4 + r));
                if (ac2[r] >= athr1) m1 |= (1u << (cg * 4 + r));
            }
        }
        mask32[tA * MST + c * 4 + lhi] = m0;      // lane-local, no shfl/atomic
        mask32[tB * MST + c * 4 + lhi] = m1;
    }
    __syncthreads();                              // masks visible (barrier #2)

    // ---- rerank: 2 threads/token, frozen-exact, order-independent key min ----
    {
        const int tok_l = tid >> 1, sub = tid & 1;
        const int tok = blockIdx.x * 128 + tok_l;
        const int tb = tok >> 12, thw = tok & 4095;
        const float* x = in + (size_t)tb * (D * HW) + thw;
        float xv[D];
#pragma unroll
        for (int d = 0; d < D; ++d) xv[d] = x[(size_t)d * HW];
        const float a = np_sum64_sq(xv);                      // frozen

        u64 best = ~0ull;
        int kp = -1;
        int pos = 0;
        for (int w32 = 0; w32 < 32; ++w32) {
            unsigned m = mask32[tok_l * MST + w32];
            const int kbase = (w32 >> 2) * 128 + (w32 & 3) * 4;
            while (m) {
                const int bit = (int)__builtin_ctz(m);
                m &= m - 1;
                const int k = kbase + (bit >> 2) * 16 + (bit & 3);
                if (((pos++) & 1) != sub) continue;
                if (kp < 0) { kp = k; continue; }
                // pair: two independent frozen chains (each sequential asc d)
                const float4* e0q = reinterpret_cast<const float4*>(cb + (size_t)kp * D);
                const float4* e1q = reinterpret_cast<const float4*>(cb + (size_t)k * D);
                float d0 = 0.f, d1 = 0.f;
#pragma unroll
                for (int i = 0; i < 16; ++i) {
                    float4 a4 = e0q[i], b4 = e1q[i];
                    float x0 = xv[4*i+0], x1 = xv[4*i+1];
                    float x2 = xv[4*i+2], x3 = xv[4*i+3];
                    d0 = __fmaf_rn(x0, a4.x, d0); d0 = __fmaf_rn(x1, a4.y, d0);
                    d0 = __fmaf_rn(x2, a4.z, d0); d0 = __fmaf_rn(x3, a4.w, d0);
                    d1 = __fmaf_rn(x0, b4.x, d1); d1 = __fmaf_rn(x1, b4.y, d1);
                    d1 = __fmaf_rn(x2, b4.z, d1); d1 = __fmaf_rn(x3, b4.w, d1);
                }
                float q0 = __fsub_rn(__fadd_rn(a, bn_g[kp]), __fmul_rn(2.0f, d0));
                float q1 = __fsub_rn(__fadd_rn(a, bn_g[k]),  __fmul_rn(2.0f, d1));
                u64 key0 = (((u64)__float_as_uint(q0)) << 32) | (unsigned)kp;
                u64 key1 = (((u64)__float_as_uint(q1)) << 32) | (unsigned)k;
                u64 kmin = key0 < key1 ? key0 : key1;
                best = best < kmin ? best : kmin;
                kp = -1;
            }
        }
        if (kp >= 0) {                           // leftover single
            const float4* e0q = reinterpret_cast<const float4*>(cb + (size_t)kp * D);
            float d0 = 0.f;
#pragma unroll
            for (int i = 0; i < 16; ++i) {
                float4 a4 = e0q[i];
                d0 = __fmaf_rn(xv[4*i+0], a4.x, d0);
                d0 = __fmaf_rn(xv[4*i+1], a4.y, d0);
                d0 = __fmaf_rn(xv[4*i+2], a4.z, d0);
                d0 = __fmaf_rn(xv[4*i+3], a4.w, d0);
            }
            float q0 = __fsub_rn(__fadd_rn(a, bn_g[kp]), __fmul_rn(2.0f, d0));
            u64 key0 = (((u64)__float_as_uint(q0)) << 32) | (unsigned)kp;
            best = best < key0 ? best : key0;
        }
        {
            u64 v = __shfl_xor(best, 1);         // tid and tid^1 share a wave
            best = best < v ? best : v;
        }
        if (sub == 0) win_s[tok_l] = (unsigned short)(best & 0x3FFull);
    }
    __syncthreads();                              // win visible (barrier #3)

    // ---- gather: 2 threads/token write the winning codebook row ----
    {
        const int tok_l = tid >> 1, half = tid & 1;
        const int tok = blockIdx.x * 128 + tok_l;
        const int gb = tok >> 12, ghw = tok & 4095;
        const unsigned k = win_s[tok_l];
        const float4* er = reinterpret_cast<const float4*>(cb + (size_t)k * D + half * 32);
        float* ot = out + (size_t)gb * (D * HW) + ghw;
#pragma unroll
        for (int i = 0; i < 8; ++i) {
            float4 e = er[i];
            ot[(size_t)(half * 32 + 4*i + 0) * HW] = e.x;
            ot[(size_t)(half * 32 + 4*i + 1) * HW] = e.y;
            ot[(size_t)(half * 32 + 4*i + 2) * HW] = e.z;
            ot[(size_t)(half * 32 + 4*i + 3) * HW] = e.w;
        }
    }
}

extern "C" void kernel_launch(void* const* d_in, const int* in_sizes, int n_in,
                              void* d_out, int out_size, void* d_ws, size_t ws_size,
                              hipStream_t stream) {
    const float* in  = (const float*)d_in[0];
    const float* cb  = (const float*)d_in[1];
    float*       out = (float*)d_out;
    char*        ws  = (char*)d_ws;

    float*          bn  = (float*)(ws + WS_BN);
    unsigned short* ebf = (unsigned short*)(ws + WS_EBF);

    hipLaunchKernelGGL(kP_prep, dim3(256), dim3(256), 0, stream, cb, bn, ebf);
    hipLaunchKernelGGL(k_mega,  dim3(512), dim3(256), 0, stream, in, ebf, bn, cb, out);
}